// Round 2
// baseline (321.466 us; speedup 1.0000x reference)
//
#include <hip/hip_runtime.h>

#define NNODES 100000
#define NEDGES 1600000
#define HID 16
#define MSG 16
#define NTYPE 16
#define NCLS 64

#define SCAN_CHUNK 1024
#define NB_SCAN ((NNODES + SCAN_CHUNK - 1) / SCAN_CHUNK)   // 98
#define TSTRIDE 257   // LDS stride for A tiles: 257 mod 32 == 1 -> etype spreads banks

__device__ __forceinline__ float sigmoid_f(float x) {
    return 1.0f / (1.0f + __expf(-x));
}

__device__ __forceinline__ float tanh_f(float x) {
    x = fminf(fmaxf(x, -15.0f), 15.0f);
    float e = __expf(2.0f * x);
    return (e - 1.0f) / (e + 1.0f);
}

// ---------------------------------------------------------------------------
// CSR build: histogram -> exclusive scan (3 small kernels) -> scatter
// ---------------------------------------------------------------------------
__global__ __launch_bounds__(256) void hist_k(const int* __restrict__ dst,
                                              int* __restrict__ cnt) {
    int e = blockIdx.x * 256 + threadIdx.x;
    if (e < NEDGES) atomicAdd(&cnt[dst[e]], 1);
}

__global__ __launch_bounds__(256) void scan_bsum(const int* __restrict__ cnt,
                                                 int* __restrict__ bsum) {
    int base = blockIdx.x * SCAN_CHUNK + threadIdx.x * 4;
    int s = 0;
    #pragma unroll
    for (int q = 0; q < 4; q++) {
        int idx = base + q;
        if (idx < NNODES) s += cnt[idx];
    }
    #pragma unroll
    for (int d = 32; d > 0; d >>= 1) s += __shfl_down(s, d, 64);
    __shared__ int ws[4];
    int lane = threadIdx.x & 63, wid = threadIdx.x >> 6;
    if (lane == 0) ws[wid] = s;
    __syncthreads();
    if (threadIdx.x == 0) bsum[blockIdx.x] = ws[0] + ws[1] + ws[2] + ws[3];
}

__global__ __launch_bounds__(128) void scan_top(int* __restrict__ bsum,
                                                int* __restrict__ rowptr) {
    int t = threadIdx.x;                      // 128 threads, NB_SCAN <= 128
    int v = (t < NB_SCAN) ? bsum[t] : 0;
    int lane = t & 63, wid = t >> 6;
    int s = v;
    #pragma unroll
    for (int d = 1; d < 64; d <<= 1) {
        int u = __shfl_up(s, d, 64);
        if (lane >= d) s += u;
    }
    __shared__ int wtot[2];
    if (lane == 63) wtot[wid] = s;
    __syncthreads();
    int excl = s - v + (wid == 1 ? wtot[0] : 0);
    if (t < NB_SCAN) bsum[t] = excl;
    if (t == 0) rowptr[NNODES] = NEDGES;
}

// reads cnt (in cntpos), writes rowptr[] and resets cntpos[] to the cursor
__global__ __launch_bounds__(256) void scan_write(const int* __restrict__ bsum,
                                                  int* __restrict__ cntpos,
                                                  int* __restrict__ rowptr) {
    int t = threadIdx.x;
    int base = blockIdx.x * SCAN_CHUNK + t * 4;
    int v[4];
    int ts = 0;
    #pragma unroll
    for (int q = 0; q < 4; q++) {
        int idx = base + q;
        v[q] = (idx < NNODES) ? cntpos[idx] : 0;
        ts += v[q];
    }
    int s = ts;
    int lane = t & 63, wid = t >> 6;
    #pragma unroll
    for (int d = 1; d < 64; d <<= 1) {
        int u = __shfl_up(s, d, 64);
        if (lane >= d) s += u;
    }
    __shared__ int wsum[4];
    if (lane == 63) wsum[wid] = s;
    __syncthreads();
    int wbase = 0;
    for (int w = 0; w < wid; w++) wbase += wsum[w];
    int off = bsum[blockIdx.x] + wbase + (s - ts);   // exclusive prefix
    #pragma unroll
    for (int q = 0; q < 4; q++) {
        int idx = base + q;
        if (idx < NNODES) {
            rowptr[idx] = off;
            cntpos[idx] = off;
        }
        off += v[q];
    }
}

__global__ __launch_bounds__(256) void scatter_k(const int* __restrict__ src,
                                                 const int* __restrict__ dst,
                                                 const int* __restrict__ et,
                                                 int* __restrict__ pos,
                                                 int* __restrict__ rec) {
    int e = blockIdx.x * 256 + threadIdx.x;
    if (e < NEDGES) {
        int d = dst[e];
        int p = atomicAdd(&pos[d], 1);
        rec[p] = src[e] | (et[e] << 17);    // src < 2^17, etype < 16
    }
}

// ---------------------------------------------------------------------------
// Aggregate: 16 lanes per node, lane i accumulates m[node][i] in a register.
// ---------------------------------------------------------------------------
__global__ __launch_bounds__(256) void agg_k(const float* __restrict__ feat,
                                             const int* __restrict__ rowptr,
                                             const int* __restrict__ rec,
                                             const float* __restrict__ edge_emb,
                                             float* __restrict__ magg) {
    __shared__ float At[NTYPE * TSTRIDE];
    for (int idx = threadIdx.x; idx < NTYPE * MSG * HID; idx += 256) {
        int t   = idx >> 8;
        int rem = idx & 255;
        int i   = rem >> 4;   // msg row
        int h   = rem & 15;   // hid col
        At[t * TSTRIDE + h * 16 + i] = edge_emb[idx];
    }
    __syncthreads();

    int node = blockIdx.x * 16 + (threadIdx.x >> 4);
    int i = threadIdx.x & 15;
    if (node >= NNODES) return;

    int jb = rowptr[node], je = rowptr[node + 1];
    float acc = 0.0f;
    for (int j = jb; j < je; j++) {
        int r = rec[j];
        int s = r & 0x1FFFF;
        int t = r >> 17;
        const float4* fp = (const float4*)(feat + (size_t)s * HID);
        float4 f0 = fp[0], f1 = fp[1], f2 = fp[2], f3 = fp[3];
        const float* a = At + t * TSTRIDE + i;
        acc += a[0*16]*f0.x + a[1*16]*f0.y + a[2*16]*f0.z + a[3*16]*f0.w;
        acc += a[4*16]*f1.x + a[5*16]*f1.y + a[6*16]*f1.z + a[7*16]*f1.w;
        acc += a[8*16]*f2.x + a[9*16]*f2.y + a[10*16]*f2.z + a[11*16]*f2.w;
        acc += a[12*16]*f3.x + a[13*16]*f3.y + a[14*16]*f3.z + a[15*16]*f3.w;
    }
    magg[(size_t)node * MSG + i] = acc;
}

// ---------------------------------------------------------------------------
// Fallback atomic edge kernel (used only if ws too small for CSR buffers)
// ---------------------------------------------------------------------------
__global__ __launch_bounds__(256) void ggnn_edge(
    const float* __restrict__ feat,
    const int* __restrict__ src,
    const int* __restrict__ dst,
    const int* __restrict__ etype,
    const float* __restrict__ edge_emb,
    float* __restrict__ magg)
{
    __shared__ float At[NTYPE * MSG * HID];
    for (int idx = threadIdx.x; idx < NTYPE * MSG * HID; idx += 256) {
        int t = idx >> 8, rem = idx & 255, i = rem >> 4, hh = rem & 15;
        At[(t << 8) | (hh << 4) | i] = edge_emb[idx];
    }
    __syncthreads();
    const long long total = (long long)NEDGES * MSG;
    for (long long w = (long long)blockIdx.x * 256 + threadIdx.x; w < total;
         w += (long long)gridDim.x * 256) {
        const int e = (int)(w >> 4);
        const int i = (int)(w & 15);
        const int s = src[e];
        const int d = dst[e];
        const int t = etype[e];
        const float4* fp = (const float4*)(feat + (size_t)s * HID);
        const float4 f0 = fp[0], f1 = fp[1], f2 = fp[2], f3 = fp[3];
        const float* a = At + (t << 8) + i;
        float acc;
        acc  = a[0*16]*f0.x + a[1*16]*f0.y + a[2*16]*f0.z + a[3*16]*f0.w;
        acc += a[4*16]*f1.x + a[5*16]*f1.y + a[6*16]*f1.z + a[7*16]*f1.w;
        acc += a[8*16]*f2.x + a[9*16]*f2.y + a[10*16]*f2.z + a[11*16]*f2.w;
        acc += a[12*16]*f3.x + a[13*16]*f3.y + a[14*16]*f3.z + a[15*16]*f3.w;
        atomicAdd(magg + (size_t)d * MSG + i, acc);
    }
}

// ---------------------------------------------------------------------------
// Node kernel: GRU + output head (unchanged this round — control)
// ---------------------------------------------------------------------------
__global__ __launch_bounds__(256) void ggnn_node(
    const float* __restrict__ feat,
    const float* __restrict__ magg,
    const float* __restrict__ W_ih,
    const float* __restrict__ W_hh,
    const float* __restrict__ b_ih,
    const float* __restrict__ b_hh,
    const float* __restrict__ W_out,
    const float* __restrict__ b_out,
    float* __restrict__ out)
{
    const int n = blockIdx.x * 256 + threadIdx.x;
    if (n >= NNODES) return;

    float hv[HID], mv[MSG];
    {
        const float4* hp = (const float4*)(feat + (size_t)n * HID);
        const float4* mp = (const float4*)(magg + (size_t)n * MSG);
        #pragma unroll
        for (int q = 0; q < 4; q++) {
            float4 a = hp[q];
            hv[4*q+0] = a.x; hv[4*q+1] = a.y; hv[4*q+2] = a.z; hv[4*q+3] = a.w;
            float4 b = mp[q];
            mv[4*q+0] = b.x; mv[4*q+1] = b.y; mv[4*q+2] = b.z; mv[4*q+3] = b.w;
        }
    }

    float hnew[HID];
    #pragma unroll
    for (int i = 0; i < HID; i++) {
        float xr = b_ih[i], xz = b_ih[16 + i], xn = b_ih[32 + i];
        float hr = b_hh[i], hz = b_hh[16 + i], hn = b_hh[32 + i];
        #pragma unroll
        for (int j = 0; j < HID; j++) {
            xr += W_ih[(i)      * 16 + j] * mv[j];
            xz += W_ih[(16 + i) * 16 + j] * mv[j];
            xn += W_ih[(32 + i) * 16 + j] * mv[j];
            hr += W_hh[(i)      * 16 + j] * hv[j];
            hz += W_hh[(16 + i) * 16 + j] * hv[j];
            hn += W_hh[(32 + i) * 16 + j] * hv[j];
        }
        float r  = sigmoid_f(xr + hr);
        float z  = sigmoid_f(xz + hz);
        float nn = tanh_f(xn + r * hn);
        hnew[i] = (1.0f - z) * nn + z * hv[i];
    }

    float4* op = (float4*)(out + (size_t)n * NCLS);
    #pragma unroll
    for (int c4 = 0; c4 < NCLS / 4; c4++) {
        float a0 = b_out[4*c4+0], a1 = b_out[4*c4+1], a2 = b_out[4*c4+2], a3 = b_out[4*c4+3];
        #pragma unroll
        for (int j = 0; j < HID; j++) {
            a0 += W_out[(4*c4+0) * 16 + j] * hnew[j];
            a1 += W_out[(4*c4+1) * 16 + j] * hnew[j];
            a2 += W_out[(4*c4+2) * 16 + j] * hnew[j];
            a3 += W_out[(4*c4+3) * 16 + j] * hnew[j];
        }
        float4 o; o.x = a0; o.y = a1; o.z = a2; o.w = a3;
        op[c4] = o;
    }
}

extern "C" void kernel_launch(void* const* d_in, const int* in_sizes, int n_in,
                              void* d_out, int out_size, void* d_ws, size_t ws_size,
                              hipStream_t stream) {
    const float* feat     = (const float*)d_in[0];
    const int*   src      = (const int*)d_in[1];
    const int*   dst      = (const int*)d_in[2];
    const int*   etype    = (const int*)d_in[3];
    const float* edge_emb = (const float*)d_in[4];
    const float* W_ih     = (const float*)d_in[5];
    const float* W_hh     = (const float*)d_in[6];
    const float* b_ih     = (const float*)d_in[7];
    const float* b_hh     = (const float*)d_in[8];
    const float* W_out    = (const float*)d_in[9];
    const float* b_out    = (const float*)d_in[10];
    float* out = (float*)d_out;

    // workspace layout (all 4-byte elements)
    float* magg   = (float*)d_ws;                       // NNODES*16 floats
    int*   rowptr = (int*)d_ws + NNODES * MSG;          // NNODES+1
    int*   cntpos = rowptr + (NNODES + 1);              // NNODES (cnt, then cursor)
    int*   bsum   = cntpos + NNODES;                    // NB_SCAN (pad to 128)
    int*   rec    = bsum + 128;                         // NEDGES
    size_t need   = ((size_t)NNODES * MSG + (NNODES + 1) + NNODES + 128 + NEDGES) * 4;

    if (ws_size >= need) {
        hipMemsetAsync(cntpos, 0, (size_t)NNODES * sizeof(int), stream);
        hist_k    <<<(NEDGES + 255) / 256, 256, 0, stream>>>(dst, cntpos);
        scan_bsum <<<NB_SCAN, 256, 0, stream>>>(cntpos, bsum);
        scan_top  <<<1, 128, 0, stream>>>(bsum, rowptr);
        scan_write<<<NB_SCAN, 256, 0, stream>>>(bsum, cntpos, rowptr);
        scatter_k <<<(NEDGES + 255) / 256, 256, 0, stream>>>(src, dst, etype, cntpos, rec);
        agg_k     <<<NNODES / 16, 256, 0, stream>>>(feat, rowptr, rec, edge_emb, magg);
    } else {
        hipMemsetAsync(magg, 0, (size_t)NNODES * MSG * sizeof(float), stream);
        ggnn_edge<<<2560, 256, 0, stream>>>(feat, src, dst, etype, edge_emb, magg);
    }
    ggnn_node<<<(NNODES + 255) / 256, 256, 0, stream>>>(
        feat, magg, W_ih, W_hh, b_ih, b_hh, W_out, b_out, out);
}

// Round 3
// 303.255 us; speedup vs baseline: 1.0601x; 1.0601x over previous
//
#include <hip/hip_runtime.h>

#define NNODES 100000
#define NEDGES 1600000
#define HID 16
#define MSG 16
#define NTYPE 16
#define NCLS 64

#define CHSZ 4096
#define NCH ((NEDGES + CHSZ - 1) / CHSZ)    // 391 edge chunks
#define NBK ((NNODES + 255) / 256)          // 391 buckets of 256 nodes (dst>>8)
#define M_SCAN (NBK * NCH)                  // 152881
#define SCH 1024
#define NSB ((M_SCAN + SCH - 1) / SCH)      // 150

__device__ __forceinline__ float sigmoid_f(float x) {
    return 1.0f / (1.0f + __expf(-x));
}
__device__ __forceinline__ float tanh_f(float x) {
    x = fminf(fmaxf(x, -15.0f), 15.0f);
    float e = __expf(2.0f * x);
    return (e - 1.0f) / (e + 1.0f);
}

// ---------------------------------------------------------------------------
// Phase A: per-chunk bucket histogram (LDS, no global atomics)
// cntmat[b * NCH + ch] = #edges of chunk ch with dst>>8 == b
// ---------------------------------------------------------------------------
__global__ __launch_bounds__(256) void hist_k(const int* __restrict__ dst,
                                              int* __restrict__ cntmat) {
    __shared__ int cnt[NBK];
    const int t = threadIdx.x, ch = blockIdx.x;
    for (int b = t; b < NBK; b += 256) cnt[b] = 0;
    __syncthreads();
    #pragma unroll
    for (int k = 0; k < CHSZ / 256; k++) {
        int e = ch * CHSZ + k * 256 + t;
        if (e < NEDGES) atomicAdd(&cnt[dst[e] >> 8], 1);
    }
    __syncthreads();
    for (int b = t; b < NBK; b += 256) cntmat[b * NCH + ch] = cnt[b];
}

// ---------------------------------------------------------------------------
// Phase B: exclusive scan of cntmat (bucket-major), in place. 3 kernels.
// ---------------------------------------------------------------------------
__global__ __launch_bounds__(256) void scan_bsum(const int* __restrict__ x,
                                                 int* __restrict__ bsum) {
    const int t = threadIdx.x;
    int base = blockIdx.x * SCH + t * 4;
    int s = 0;
    #pragma unroll
    for (int q = 0; q < 4; q++) {
        int idx = base + q;
        if (idx < M_SCAN) s += x[idx];
    }
    #pragma unroll
    for (int d = 32; d > 0; d >>= 1) s += __shfl_down(s, d, 64);
    __shared__ int ws[4];
    int lane = t & 63, w = t >> 6;
    if (lane == 0) ws[w] = s;
    __syncthreads();
    if (t == 0) bsum[blockIdx.x] = ws[0] + ws[1] + ws[2] + ws[3];
}

__global__ __launch_bounds__(256) void scan_top(int* __restrict__ bsum) {
    const int t = threadIdx.x;
    int v = (t < NSB) ? bsum[t] : 0;
    int lane = t & 63, w = t >> 6;
    int s = v;
    #pragma unroll
    for (int d = 1; d < 64; d <<= 1) {
        int u = __shfl_up(s, d, 64);
        if (lane >= d) s += u;
    }
    __shared__ int ws[4];
    if (lane == 63) ws[w] = s;
    __syncthreads();
    int base = 0;
    #pragma unroll
    for (int q = 0; q < 4; q++) if (q < w) base += ws[q];
    if (t < NSB) bsum[t] = base + s - v;
}

__global__ __launch_bounds__(256) void scan_write(const int* __restrict__ bsum,
                                                  int* __restrict__ x) {
    const int t = threadIdx.x;
    int base = blockIdx.x * SCH + t * 4;
    int v[4]; int ts = 0;
    #pragma unroll
    for (int q = 0; q < 4; q++) {
        int idx = base + q;
        v[q] = (idx < M_SCAN) ? x[idx] : 0;
        ts += v[q];
    }
    int lane = t & 63, w = t >> 6;
    int s = ts;
    #pragma unroll
    for (int d = 1; d < 64; d <<= 1) {
        int u = __shfl_up(s, d, 64);
        if (lane >= d) s += u;
    }
    __shared__ int ws[4];
    if (lane == 63) ws[w] = s;
    __syncthreads();
    int wbase = 0;
    #pragma unroll
    for (int q = 0; q < 4; q++) if (q < w) wbase += ws[q];
    int run = bsum[blockIdx.x] + wbase + (s - ts);
    #pragma unroll
    for (int q = 0; q < 4; q++) {
        int idx = base + q;
        if (idx < M_SCAN) x[idx] = run;
        run += v[q];
    }
}

// ---------------------------------------------------------------------------
// Phase C: scatter into bucket-grouped record array. Cursors live in LDS
// (per-chunk column of the offset matrix); each (chunk,bucket) segment is
// contiguous -> spatially clustered writes, zero global atomics.
// rec = src | etype<<17 | (dst&255)<<21
// ---------------------------------------------------------------------------
__global__ __launch_bounds__(256) void scatter_k(const int* __restrict__ src,
                                                 const int* __restrict__ dst,
                                                 const int* __restrict__ et,
                                                 const int* __restrict__ offmat,
                                                 int* __restrict__ rec) {
    __shared__ int offc[NBK];
    const int t = threadIdx.x, ch = blockIdx.x;
    for (int b = t; b < NBK; b += 256) offc[b] = offmat[b * NCH + ch];
    __syncthreads();
    #pragma unroll
    for (int k = 0; k < CHSZ / 256; k++) {
        int e = ch * CHSZ + k * 256 + t;
        if (e < NEDGES) {
            int d = dst[e];
            int b = d >> 8;
            int pos = atomicAdd(&offc[b], 1);      // LDS atomic
            rec[pos] = src[e] | (et[e] << 17) | ((d & 255) << 21);
        }
    }
}

// ---------------------------------------------------------------------------
// Phase D: per-bucket aggregation. Block = bucket (256 nodes). Accumulator in
// LDS (ds_add_f32), 16 lanes per edge, 2x unrolled. magg written coalesced.
// ---------------------------------------------------------------------------
__global__ __launch_bounds__(256) void agg_k(const float* __restrict__ feat,
                                             const int* __restrict__ offmat,
                                             const int* __restrict__ rec,
                                             const float* __restrict__ edge_emb,
                                             float* __restrict__ magg) {
    __shared__ float At[NTYPE * 257];      // [t][h*16+i], stride 257 spreads banks
    __shared__ float acc[256 * 17];        // [localnode][i], stride 17
    const int t = threadIdx.x, b = blockIdx.x;

    for (int idx = t; idx < NTYPE * MSG * HID; idx += 256) {
        int ty  = idx >> 8;
        int rem = idx & 255;
        int i   = rem >> 4;
        int h   = rem & 15;
        At[ty * 257 + h * 16 + i] = edge_emb[idx];
    }
    for (int k = t; k < 256 * 17; k += 256) acc[k] = 0.0f;
    __syncthreads();

    const int jb = offmat[b * NCH];
    const int je = (b == NBK - 1) ? NEDGES : offmat[(b + 1) * NCH];
    const int g = t >> 4, i = t & 15;

    int j = jb + g;
    for (; j + 16 < je; j += 32) {
        int r0 = rec[j], r1 = rec[j + 16];
        int s0 = r0 & 0x1FFFF, ty0 = (r0 >> 17) & 15, ld0 = r0 >> 21;
        int s1 = r1 & 0x1FFFF, ty1 = (r1 >> 17) & 15, ld1 = r1 >> 21;
        const float4* fp0 = (const float4*)(feat + (size_t)s0 * HID);
        const float4* fp1 = (const float4*)(feat + (size_t)s1 * HID);
        float4 a0 = fp0[0], a1 = fp0[1], a2 = fp0[2], a3 = fp0[3];
        float4 c0 = fp1[0], c1 = fp1[1], c2 = fp1[2], c3 = fp1[3];
        const float* pa = At + ty0 * 257 + i;
        const float* pb = At + ty1 * 257 + i;
        float m0, m1;
        m0  = pa[0*16]*a0.x + pa[1*16]*a0.y + pa[2*16]*a0.z + pa[3*16]*a0.w;
        m0 += pa[4*16]*a1.x + pa[5*16]*a1.y + pa[6*16]*a1.z + pa[7*16]*a1.w;
        m0 += pa[8*16]*a2.x + pa[9*16]*a2.y + pa[10*16]*a2.z + pa[11*16]*a2.w;
        m0 += pa[12*16]*a3.x + pa[13*16]*a3.y + pa[14*16]*a3.z + pa[15*16]*a3.w;
        m1  = pb[0*16]*c0.x + pb[1*16]*c0.y + pb[2*16]*c0.z + pb[3*16]*c0.w;
        m1 += pb[4*16]*c1.x + pb[5*16]*c1.y + pb[6*16]*c1.z + pb[7*16]*c1.w;
        m1 += pb[8*16]*c2.x + pb[9*16]*c2.y + pb[10*16]*c2.z + pb[11*16]*c2.w;
        m1 += pb[12*16]*c3.x + pb[13*16]*c3.y + pb[14*16]*c3.z + pb[15*16]*c3.w;
        atomicAdd(&acc[ld0 * 17 + i], m0);
        atomicAdd(&acc[ld1 * 17 + i], m1);
    }
    if (j < je) {
        int r0 = rec[j];
        int s0 = r0 & 0x1FFFF, ty0 = (r0 >> 17) & 15, ld0 = r0 >> 21;
        const float4* fp0 = (const float4*)(feat + (size_t)s0 * HID);
        float4 a0 = fp0[0], a1 = fp0[1], a2 = fp0[2], a3 = fp0[3];
        const float* pa = At + ty0 * 257 + i;
        float m0;
        m0  = pa[0*16]*a0.x + pa[1*16]*a0.y + pa[2*16]*a0.z + pa[3*16]*a0.w;
        m0 += pa[4*16]*a1.x + pa[5*16]*a1.y + pa[6*16]*a1.z + pa[7*16]*a1.w;
        m0 += pa[8*16]*a2.x + pa[9*16]*a2.y + pa[10*16]*a2.z + pa[11*16]*a2.w;
        m0 += pa[12*16]*a3.x + pa[13*16]*a3.y + pa[14*16]*a3.z + pa[15*16]*a3.w;
        atomicAdd(&acc[ld0 * 17 + i], m0);
    }
    __syncthreads();

    const int nb = b * 256;
    for (int k = t; k < 256 * 16; k += 256) {
        int ln = k >> 4, ii = k & 15;
        int n = nb + ln;
        if (n < NNODES) magg[(size_t)n * MSG + ii] = acc[ln * 17 + ii];
    }
}

// ---------------------------------------------------------------------------
// Fallback atomic edge kernel (only if ws too small)
// ---------------------------------------------------------------------------
__global__ __launch_bounds__(256) void ggnn_edge(
    const float* __restrict__ feat,
    const int* __restrict__ src,
    const int* __restrict__ dst,
    const int* __restrict__ etype,
    const float* __restrict__ edge_emb,
    float* __restrict__ magg)
{
    __shared__ float At[NTYPE * MSG * HID];
    for (int idx = threadIdx.x; idx < NTYPE * MSG * HID; idx += 256) {
        int ty = idx >> 8, rem = idx & 255, i = rem >> 4, hh = rem & 15;
        At[(ty << 8) | (hh << 4) | i] = edge_emb[idx];
    }
    __syncthreads();
    const long long total = (long long)NEDGES * MSG;
    for (long long w = (long long)blockIdx.x * 256 + threadIdx.x; w < total;
         w += (long long)gridDim.x * 256) {
        const int e = (int)(w >> 4);
        const int i = (int)(w & 15);
        const int s = src[e];
        const int d = dst[e];
        const int ty = etype[e];
        const float4* fp = (const float4*)(feat + (size_t)s * HID);
        const float4 f0 = fp[0], f1 = fp[1], f2 = fp[2], f3 = fp[3];
        const float* a = At + (ty << 8) + i;
        float m;
        m  = a[0*16]*f0.x + a[1*16]*f0.y + a[2*16]*f0.z + a[3*16]*f0.w;
        m += a[4*16]*f1.x + a[5*16]*f1.y + a[6*16]*f1.z + a[7*16]*f1.w;
        m += a[8*16]*f2.x + a[9*16]*f2.y + a[10*16]*f2.z + a[11*16]*f2.w;
        m += a[12*16]*f3.x + a[13*16]*f3.y + a[14*16]*f3.z + a[15*16]*f3.w;
        atomicAdd(magg + (size_t)d * MSG + i, m);
    }
}

// ---------------------------------------------------------------------------
// Node kernel: GRU phase -> hnew in LDS -> coalesced output head.
// Per-thread class c is fixed in the output phase -> W_out row hoisted to regs.
// ---------------------------------------------------------------------------
__global__ __launch_bounds__(256) void node_k(
    const float* __restrict__ feat,
    const float* __restrict__ magg,
    const float* __restrict__ W_ih,
    const float* __restrict__ W_hh,
    const float* __restrict__ b_ih,
    const float* __restrict__ b_hh,
    const float* __restrict__ W_out,
    const float* __restrict__ b_out,
    float* __restrict__ out)
{
    __shared__ float hn_s[256 * 20];     // [localnode][j], stride 20 (16B-aligned)
    __shared__ float Wo_s[NCLS * 17];    // [c][j], stride 17 (bank-spread)
    __shared__ float bo_s[NCLS];

    const int t = threadIdx.x;
    for (int k = t; k < NCLS * 16; k += 256) Wo_s[(k >> 4) * 17 + (k & 15)] = W_out[k];
    if (t < NCLS) bo_s[t] = b_out[t];

    const int n = blockIdx.x * 256 + t;
    if (n < NNODES) {
        float hv[HID], mv[MSG];
        const float4* hp = (const float4*)(feat + (size_t)n * HID);
        const float4* mp = (const float4*)(magg + (size_t)n * MSG);
        #pragma unroll
        for (int q = 0; q < 4; q++) {
            float4 a = hp[q];
            hv[4*q+0] = a.x; hv[4*q+1] = a.y; hv[4*q+2] = a.z; hv[4*q+3] = a.w;
            float4 c = mp[q];
            mv[4*q+0] = c.x; mv[4*q+1] = c.y; mv[4*q+2] = c.z; mv[4*q+3] = c.w;
        }
        #pragma unroll
        for (int i = 0; i < HID; i++) {
            float xr = b_ih[i], xz = b_ih[16 + i], xn = b_ih[32 + i];
            float hr = b_hh[i], hz = b_hh[16 + i], hn = b_hh[32 + i];
            #pragma unroll
            for (int j = 0; j < HID; j++) {
                xr += W_ih[(i)      * 16 + j] * mv[j];
                xz += W_ih[(16 + i) * 16 + j] * mv[j];
                xn += W_ih[(32 + i) * 16 + j] * mv[j];
                hr += W_hh[(i)      * 16 + j] * hv[j];
                hz += W_hh[(16 + i) * 16 + j] * hv[j];
                hn += W_hh[(32 + i) * 16 + j] * hv[j];
            }
            float r  = sigmoid_f(xr + hr);
            float z  = sigmoid_f(xz + hz);
            float nn = tanh_f(xn + r * hn);
            hn_s[t * 20 + i] = (1.0f - z) * nn + z * hv[i];
        }
    }
    __syncthreads();

    // Output phase: c = t&63 is constant per thread; ln walks 4 nodes/iter apart
    const int c = t & 63;
    float wr[16];
    #pragma unroll
    for (int j = 0; j < 16; j++) wr[j] = Wo_s[c * 17 + j];
    const float bo = bo_s[c];
    const int nb = blockIdx.x * 256;

    #pragma unroll 4
    for (int it = 0; it < 64; it++) {
        int k = t + 256 * it;
        int ln = k >> 6;
        int n2 = nb + ln;
        if (n2 < NNODES) {
            const float4* hq = (const float4*)(hn_s + ln * 20);
            float4 h0 = hq[0], h1 = hq[1], h2 = hq[2], h3 = hq[3];
            float a = bo;
            a += wr[0]*h0.x + wr[1]*h0.y + wr[2]*h0.z + wr[3]*h0.w;
            a += wr[4]*h1.x + wr[5]*h1.y + wr[6]*h1.z + wr[7]*h1.w;
            a += wr[8]*h2.x + wr[9]*h2.y + wr[10]*h2.z + wr[11]*h2.w;
            a += wr[12]*h3.x + wr[13]*h3.y + wr[14]*h3.z + wr[15]*h3.w;
            out[(size_t)n2 * NCLS + c] = a;
        }
    }
}

extern "C" void kernel_launch(void* const* d_in, const int* in_sizes, int n_in,
                              void* d_out, int out_size, void* d_ws, size_t ws_size,
                              hipStream_t stream) {
    const float* feat     = (const float*)d_in[0];
    const int*   src      = (const int*)d_in[1];
    const int*   dst      = (const int*)d_in[2];
    const int*   etype    = (const int*)d_in[3];
    const float* edge_emb = (const float*)d_in[4];
    const float* W_ih     = (const float*)d_in[5];
    const float* W_hh     = (const float*)d_in[6];
    const float* b_ih     = (const float*)d_in[7];
    const float* b_hh     = (const float*)d_in[8];
    const float* W_out    = (const float*)d_in[9];
    const float* b_out    = (const float*)d_in[10];
    float* out = (float*)d_out;

    // workspace layout (4-byte elements)
    float* magg   = (float*)d_ws;                         // NNODES*16
    int*   offmat = (int*)d_ws + (size_t)NNODES * MSG;    // M_SCAN
    int*   bsum   = offmat + M_SCAN;                      // NSB (pad 256)
    int*   rec    = bsum + 256;                           // NEDGES
    size_t need   = ((size_t)NNODES * MSG + M_SCAN + 256 + NEDGES) * 4;

    if (ws_size >= need) {
        hist_k    <<<NCH, 256, 0, stream>>>(dst, offmat);
        scan_bsum <<<NSB, 256, 0, stream>>>(offmat, bsum);
        scan_top  <<<1, 256, 0, stream>>>(bsum);
        scan_write<<<NSB, 256, 0, stream>>>(bsum, offmat);
        scatter_k <<<NCH, 256, 0, stream>>>(src, dst, etype, offmat, rec);
        agg_k     <<<NBK, 256, 0, stream>>>(feat, offmat, rec, edge_emb, magg);
    } else {
        hipMemsetAsync(magg, 0, (size_t)NNODES * MSG * sizeof(float), stream);
        ggnn_edge<<<2560, 256, 0, stream>>>(feat, src, dst, etype, edge_emb, magg);
    }
    node_k<<<(NNODES + 255) / 256, 256, 0, stream>>>(
        feat, magg, W_ih, W_hh, b_ih, b_hh, W_out, b_out, out);
}

// Round 4
// 274.739 us; speedup vs baseline: 1.1701x; 1.1038x over previous
//
#include <hip/hip_runtime.h>

#define NNODES 100000
#define NEDGES 1600000
#define HID 16
#define MSG 16
#define NTYPE 16
#define NCLS 64

#define BSH 7
#define NBK ((NNODES + 127) >> 7)           // 782 buckets of 128 nodes (dst>>7)
#define CHSZ 8192
#define NCH ((NEDGES + CHSZ - 1) / CHSZ)    // 196 edge chunks
#define M_SCAN (NBK * NCH)                  // 153,272
#define SCH 1024
#define NSB ((M_SCAN + SCH - 1) / SCH)      // 150

// At2 layout: [ty][i][h], row stride 20 floats, type stride 320 floats.
// byte quad index = (5i+q) mod 8 -> uniform 8 lanes/bank for ds_read_b128.
#define ASTR 20
#define ATY  320

__device__ __forceinline__ float sigmoid_f(float x) {
    return 1.0f / (1.0f + __expf(-x));
}
__device__ __forceinline__ float tanh_f(float x) {
    x = fminf(fmaxf(x, -15.0f), 15.0f);
    float e = __expf(2.0f * x);
    return (e - 1.0f) / (e + 1.0f);
}

// ---------------------------------------------------------------------------
// Phase A: per-chunk bucket histogram (LDS atomics only)
// ---------------------------------------------------------------------------
__global__ __launch_bounds__(256) void hist_k(const int* __restrict__ dst,
                                              int* __restrict__ cntmat) {
    __shared__ int cnt[NBK];
    const int t = threadIdx.x, ch = blockIdx.x;
    for (int b = t; b < NBK; b += 256) cnt[b] = 0;
    __syncthreads();
    #pragma unroll
    for (int k = 0; k < CHSZ / 256; k++) {
        int e = ch * CHSZ + k * 256 + t;
        if (e < NEDGES) atomicAdd(&cnt[dst[e] >> BSH], 1);
    }
    __syncthreads();
    for (int b = t; b < NBK; b += 256) cntmat[b * NCH + ch] = cnt[b];
}

// ---------------------------------------------------------------------------
// Phase B: exclusive scan of cntmat (bucket-major), in place. 3 kernels.
// ---------------------------------------------------------------------------
__global__ __launch_bounds__(256) void scan_bsum(const int* __restrict__ x,
                                                 int* __restrict__ bsum) {
    const int t = threadIdx.x;
    int base = blockIdx.x * SCH + t * 4;
    int s = 0;
    #pragma unroll
    for (int q = 0; q < 4; q++) {
        int idx = base + q;
        if (idx < M_SCAN) s += x[idx];
    }
    #pragma unroll
    for (int d = 32; d > 0; d >>= 1) s += __shfl_down(s, d, 64);
    __shared__ int ws[4];
    int lane = t & 63, w = t >> 6;
    if (lane == 0) ws[w] = s;
    __syncthreads();
    if (t == 0) bsum[blockIdx.x] = ws[0] + ws[1] + ws[2] + ws[3];
}

__global__ __launch_bounds__(256) void scan_top(int* __restrict__ bsum) {
    const int t = threadIdx.x;
    int v = (t < NSB) ? bsum[t] : 0;
    int lane = t & 63, w = t >> 6;
    int s = v;
    #pragma unroll
    for (int d = 1; d < 64; d <<= 1) {
        int u = __shfl_up(s, d, 64);
        if (lane >= d) s += u;
    }
    __shared__ int ws[4];
    if (lane == 63) ws[w] = s;
    __syncthreads();
    int base = 0;
    #pragma unroll
    for (int q = 0; q < 4; q++) if (q < w) base += ws[q];
    if (t < NSB) bsum[t] = base + s - v;
}

__global__ __launch_bounds__(256) void scan_write(const int* __restrict__ bsum,
                                                  int* __restrict__ x) {
    const int t = threadIdx.x;
    int base = blockIdx.x * SCH + t * 4;
    int v[4]; int ts = 0;
    #pragma unroll
    for (int q = 0; q < 4; q++) {
        int idx = base + q;
        v[q] = (idx < M_SCAN) ? x[idx] : 0;
        ts += v[q];
    }
    int lane = t & 63, w = t >> 6;
    int s = ts;
    #pragma unroll
    for (int d = 1; d < 64; d <<= 1) {
        int u = __shfl_up(s, d, 64);
        if (lane >= d) s += u;
    }
    __shared__ int ws[4];
    if (lane == 63) ws[w] = s;
    __syncthreads();
    int wbase = 0;
    #pragma unroll
    for (int q = 0; q < 4; q++) if (q < w) wbase += ws[q];
    int run = bsum[blockIdx.x] + wbase + (s - ts);
    #pragma unroll
    for (int q = 0; q < 4; q++) {
        int idx = base + q;
        if (idx < M_SCAN) x[idx] = run;
        run += v[q];
    }
}

// ---------------------------------------------------------------------------
// Phase C: scatter into bucket-grouped records. LDS cursors, zero global
// atomics, segment-clustered writes. rec = src | et<<17 | (dst&127)<<21
// ---------------------------------------------------------------------------
__global__ __launch_bounds__(256) void scatter_k(const int* __restrict__ src,
                                                 const int* __restrict__ dst,
                                                 const int* __restrict__ et,
                                                 const int* __restrict__ offmat,
                                                 int* __restrict__ rec) {
    __shared__ int offc[NBK];
    const int t = threadIdx.x, ch = blockIdx.x;
    for (int b = t; b < NBK; b += 256) offc[b] = offmat[b * NCH + ch];
    __syncthreads();
    #pragma unroll
    for (int k = 0; k < CHSZ / 256; k++) {
        int e = ch * CHSZ + k * 256 + t;
        if (e < NEDGES) {
            int d = dst[e];
            int b = d >> BSH;
            int pos = atomicAdd(&offc[b], 1);
            rec[pos] = src[e] | (et[e] << 17) | ((d & 127) << 21);
        }
    }
}

// ---------------------------------------------------------------------------
// Phase D: per-bucket aggregation. One 512-thread block per 128-node bucket,
// 32 groups of 16 lanes, unroll-2, A rows via ds_read_b128 (conflict-free
// layout), LDS f32-atomic accumulate, single coalesced magg store.
// ---------------------------------------------------------------------------
__global__ __launch_bounds__(512) void agg_k(const float* __restrict__ feat,
                                             const int* __restrict__ offmat,
                                             const int* __restrict__ rec,
                                             const float* __restrict__ edge_emb,
                                             float* __restrict__ magg) {
    __shared__ float At2[NTYPE * ATY];     // 20.5 KB
    __shared__ float acc[128 * 17];        // 8.7 KB
    const int t = threadIdx.x, b = blockIdx.x;

    #pragma unroll
    for (int idx = t; idx < NTYPE * MSG * HID; idx += 512) {
        int ty  = idx >> 8;
        int rem = idx & 255;
        int i   = rem >> 4;
        int h   = rem & 15;
        At2[ty * ATY + i * ASTR + h] = edge_emb[idx];
    }
    for (int k = t; k < 128 * 17; k += 512) acc[k] = 0.0f;
    __syncthreads();

    const int jb = offmat[b * NCH];
    const int je = (b == NBK - 1) ? NEDGES : offmat[(b + 1) * NCH];
    const int g = t >> 4, i = t & 15;

    int j = jb + g;
    for (; j + 32 < je; j += 64) {
        int r0 = rec[j], r1 = rec[j + 32];
        int s0 = r0 & 0x1FFFF, ty0 = (r0 >> 17) & 15, ld0 = r0 >> 21;
        int s1 = r1 & 0x1FFFF, ty1 = (r1 >> 17) & 15, ld1 = r1 >> 21;
        const float4* fp0 = (const float4*)(feat + (size_t)s0 * HID);
        const float4* fp1 = (const float4*)(feat + (size_t)s1 * HID);
        float4 f0 = fp0[0], f1 = fp0[1], f2 = fp0[2], f3 = fp0[3];
        float4 e0 = fp1[0], e1 = fp1[1], e2 = fp1[2], e3 = fp1[3];
        const float4* pa = (const float4*)(At2 + ty0 * ATY + i * ASTR);
        const float4* pb = (const float4*)(At2 + ty1 * ATY + i * ASTR);
        float4 A0 = pa[0], A1 = pa[1], A2 = pa[2], A3 = pa[3];
        float4 B0 = pb[0], B1 = pb[1], B2 = pb[2], B3 = pb[3];
        float m0, m1;
        m0  = A0.x*f0.x + A0.y*f0.y + A0.z*f0.z + A0.w*f0.w;
        m0 += A1.x*f1.x + A1.y*f1.y + A1.z*f1.z + A1.w*f1.w;
        m0 += A2.x*f2.x + A2.y*f2.y + A2.z*f2.z + A2.w*f2.w;
        m0 += A3.x*f3.x + A3.y*f3.y + A3.z*f3.z + A3.w*f3.w;
        m1  = B0.x*e0.x + B0.y*e0.y + B0.z*e0.z + B0.w*e0.w;
        m1 += B1.x*e1.x + B1.y*e1.y + B1.z*e1.z + B1.w*e1.w;
        m1 += B2.x*e2.x + B2.y*e2.y + B2.z*e2.z + B2.w*e2.w;
        m1 += B3.x*e3.x + B3.y*e3.y + B3.z*e3.z + B3.w*e3.w;
        atomicAdd(&acc[ld0 * 17 + i], m0);
        atomicAdd(&acc[ld1 * 17 + i], m1);
    }
    if (j < je) {
        int r0 = rec[j];
        int s0 = r0 & 0x1FFFF, ty0 = (r0 >> 17) & 15, ld0 = r0 >> 21;
        const float4* fp0 = (const float4*)(feat + (size_t)s0 * HID);
        float4 f0 = fp0[0], f1 = fp0[1], f2 = fp0[2], f3 = fp0[3];
        const float4* pa = (const float4*)(At2 + ty0 * ATY + i * ASTR);
        float4 A0 = pa[0], A1 = pa[1], A2 = pa[2], A3 = pa[3];
        float m0;
        m0  = A0.x*f0.x + A0.y*f0.y + A0.z*f0.z + A0.w*f0.w;
        m0 += A1.x*f1.x + A1.y*f1.y + A1.z*f1.z + A1.w*f1.w;
        m0 += A2.x*f2.x + A2.y*f2.y + A2.z*f2.z + A2.w*f2.w;
        m0 += A3.x*f3.x + A3.y*f3.y + A3.z*f3.z + A3.w*f3.w;
        atomicAdd(&acc[ld0 * 17 + i], m0);
    }
    __syncthreads();

    const int nb = b << BSH;
    #pragma unroll
    for (int k = t; k < 128 * 16; k += 512) {
        int ln = k >> 4, ii = k & 15;
        int n = nb + ln;
        if (n < NNODES) magg[(size_t)n * MSG + ii] = acc[ln * 17 + ii];
    }
}

// ---------------------------------------------------------------------------
// Fallback atomic edge kernel (only if ws too small)
// ---------------------------------------------------------------------------
__global__ __launch_bounds__(256) void ggnn_edge(
    const float* __restrict__ feat,
    const int* __restrict__ src,
    const int* __restrict__ dst,
    const int* __restrict__ etype,
    const float* __restrict__ edge_emb,
    float* __restrict__ magg)
{
    __shared__ float At[NTYPE * MSG * HID];
    for (int idx = threadIdx.x; idx < NTYPE * MSG * HID; idx += 256) {
        int ty = idx >> 8, rem = idx & 255, i = rem >> 4, hh = rem & 15;
        At[(ty << 8) | (hh << 4) | i] = edge_emb[idx];
    }
    __syncthreads();
    const long long total = (long long)NEDGES * MSG;
    for (long long w = (long long)blockIdx.x * 256 + threadIdx.x; w < total;
         w += (long long)gridDim.x * 256) {
        const int e = (int)(w >> 4);
        const int i = (int)(w & 15);
        const int s = src[e];
        const int d = dst[e];
        const int ty = etype[e];
        const float4* fp = (const float4*)(feat + (size_t)s * HID);
        const float4 f0 = fp[0], f1 = fp[1], f2 = fp[2], f3 = fp[3];
        const float* a = At + (ty << 8) + i;
        float m;
        m  = a[0*16]*f0.x + a[1*16]*f0.y + a[2*16]*f0.z + a[3*16]*f0.w;
        m += a[4*16]*f1.x + a[5*16]*f1.y + a[6*16]*f1.z + a[7*16]*f1.w;
        m += a[8*16]*f2.x + a[9*16]*f2.y + a[10*16]*f2.z + a[11*16]*f2.w;
        m += a[12*16]*f3.x + a[13*16]*f3.y + a[14*16]*f3.z + a[15*16]*f3.w;
        atomicAdd(magg + (size_t)d * MSG + i, m);
    }
}

// ---------------------------------------------------------------------------
// Node kernel: GRU -> hnew in LDS -> coalesced output head.
// ---------------------------------------------------------------------------
__global__ __launch_bounds__(256) void node_k(
    const float* __restrict__ feat,
    const float* __restrict__ magg,
    const float* __restrict__ W_ih,
    const float* __restrict__ W_hh,
    const float* __restrict__ b_ih,
    const float* __restrict__ b_hh,
    const float* __restrict__ W_out,
    const float* __restrict__ b_out,
    float* __restrict__ out)
{
    __shared__ float hn_s[256 * 20];
    __shared__ float Wo_s[NCLS * 17];
    __shared__ float bo_s[NCLS];

    const int t = threadIdx.x;
    for (int k = t; k < NCLS * 16; k += 256) Wo_s[(k >> 4) * 17 + (k & 15)] = W_out[k];
    if (t < NCLS) bo_s[t] = b_out[t];

    const int n = blockIdx.x * 256 + t;
    if (n < NNODES) {
        float hv[HID], mv[MSG];
        const float4* hp = (const float4*)(feat + (size_t)n * HID);
        const float4* mp = (const float4*)(magg + (size_t)n * MSG);
        #pragma unroll
        for (int q = 0; q < 4; q++) {
            float4 a = hp[q];
            hv[4*q+0] = a.x; hv[4*q+1] = a.y; hv[4*q+2] = a.z; hv[4*q+3] = a.w;
            float4 c = mp[q];
            mv[4*q+0] = c.x; mv[4*q+1] = c.y; mv[4*q+2] = c.z; mv[4*q+3] = c.w;
        }
        #pragma unroll
        for (int i = 0; i < HID; i++) {
            float xr = b_ih[i], xz = b_ih[16 + i], xn = b_ih[32 + i];
            float hr = b_hh[i], hz = b_hh[16 + i], hn = b_hh[32 + i];
            #pragma unroll
            for (int j = 0; j < HID; j++) {
                xr += W_ih[(i)      * 16 + j] * mv[j];
                xz += W_ih[(16 + i) * 16 + j] * mv[j];
                xn += W_ih[(32 + i) * 16 + j] * mv[j];
                hr += W_hh[(i)      * 16 + j] * hv[j];
                hz += W_hh[(16 + i) * 16 + j] * hv[j];
                hn += W_hh[(32 + i) * 16 + j] * hv[j];
            }
            float r  = sigmoid_f(xr + hr);
            float z  = sigmoid_f(xz + hz);
            float nn = tanh_f(xn + r * hn);
            hn_s[t * 20 + i] = (1.0f - z) * nn + z * hv[i];
        }
    }
    __syncthreads();

    const int c = t & 63;
    float wr[16];
    #pragma unroll
    for (int j = 0; j < 16; j++) wr[j] = Wo_s[c * 17 + j];
    const float bo = bo_s[c];
    const int nb = blockIdx.x * 256;

    #pragma unroll 4
    for (int it = 0; it < 64; it++) {
        int k = t + 256 * it;
        int ln = k >> 6;
        int n2 = nb + ln;
        if (n2 < NNODES) {
            const float4* hq = (const float4*)(hn_s + ln * 20);
            float4 h0 = hq[0], h1 = hq[1], h2 = hq[2], h3 = hq[3];
            float a = bo;
            a += wr[0]*h0.x + wr[1]*h0.y + wr[2]*h0.z + wr[3]*h0.w;
            a += wr[4]*h1.x + wr[5]*h1.y + wr[6]*h1.z + wr[7]*h1.w;
            a += wr[8]*h2.x + wr[9]*h2.y + wr[10]*h2.z + wr[11]*h2.w;
            a += wr[12]*h3.x + wr[13]*h3.y + wr[14]*h3.z + wr[15]*h3.w;
            out[(size_t)n2 * NCLS + c] = a;
        }
    }
}

extern "C" void kernel_launch(void* const* d_in, const int* in_sizes, int n_in,
                              void* d_out, int out_size, void* d_ws, size_t ws_size,
                              hipStream_t stream) {
    const float* feat     = (const float*)d_in[0];
    const int*   src      = (const int*)d_in[1];
    const int*   dst      = (const int*)d_in[2];
    const int*   etype    = (const int*)d_in[3];
    const float* edge_emb = (const float*)d_in[4];
    const float* W_ih     = (const float*)d_in[5];
    const float* W_hh     = (const float*)d_in[6];
    const float* b_ih     = (const float*)d_in[7];
    const float* b_hh     = (const float*)d_in[8];
    const float* W_out    = (const float*)d_in[9];
    const float* b_out    = (const float*)d_in[10];
    float* out = (float*)d_out;

    // workspace layout (4-byte elements): 13.4 MB total
    float* magg   = (float*)d_ws;                         // NNODES*16
    int*   offmat = (int*)d_ws + (size_t)NNODES * MSG;    // M_SCAN
    int*   bsum   = offmat + M_SCAN;                      // NSB (pad 256)
    int*   rec    = bsum + 256;                           // NEDGES
    size_t need   = ((size_t)NNODES * MSG + M_SCAN + 256 + NEDGES) * 4;

    if (ws_size >= need) {
        hist_k    <<<NCH, 256, 0, stream>>>(dst, offmat);
        scan_bsum <<<NSB, 256, 0, stream>>>(offmat, bsum);
        scan_top  <<<1, 256, 0, stream>>>(bsum);
        scan_write<<<NSB, 256, 0, stream>>>(bsum, offmat);
        scatter_k <<<NCH, 256, 0, stream>>>(src, dst, etype, offmat, rec);
        agg_k     <<<NBK, 512, 0, stream>>>(feat, offmat, rec, edge_emb, magg);
    } else {
        hipMemsetAsync(magg, 0, (size_t)NNODES * MSG * sizeof(float), stream);
        ggnn_edge<<<2560, 256, 0, stream>>>(feat, src, dst, etype, edge_emb, magg);
    }
    node_k<<<(NNODES + 255) / 256, 256, 0, stream>>>(
        feat, magg, W_ih, W_hh, b_ih, b_hh, W_out, b_out, out);
}

// Round 5
// 259.993 us; speedup vs baseline: 1.2364x; 1.0567x over previous
//
#include <hip/hip_runtime.h>

#define NNODES 100000
#define NEDGES 1600000
#define HID 16
#define MSG 16
#define NTYPE 16
#define NCLS 64

#define BSH 7
#define NBK ((NNODES + 127) >> 7)           // 782 buckets of 128 nodes (dst>>7)
#define CHSZ 8192
#define NCH ((NEDGES + CHSZ - 1) / CHSZ)    // 196 edge chunks
#define M_SCAN (NBK * NCH)                  // 153,272
#define SCH 1024
#define NSB ((M_SCAN + SCH - 1) / SCH)      // 150

// At2 layout: [ty][i][h], row stride 20 floats, type stride 320 floats.
// byte-quad index = (5i+q) mod 8 -> uniform 8 lanes/bank for ds_read_b128.
#define ASTR 20
#define ATY  320

#define RECCAP 2560   // LDS staging capacity for a bucket's record segment

__device__ __forceinline__ float sigmoid_f(float x) {
    return 1.0f / (1.0f + __expf(-x));
}
__device__ __forceinline__ float tanh_f(float x) {
    x = fminf(fmaxf(x, -15.0f), 15.0f);
    float e = __expf(2.0f * x);
    return (e - 1.0f) / (e + 1.0f);
}

// ---------------------------------------------------------------------------
// Phase A: per-chunk bucket histogram (LDS atomics only)
// ---------------------------------------------------------------------------
__global__ __launch_bounds__(1024) void hist_k(const int* __restrict__ dst,
                                               int* __restrict__ cntmat) {
    __shared__ int cnt[NBK];
    const int t = threadIdx.x, ch = blockIdx.x;
    for (int b = t; b < NBK; b += 1024) cnt[b] = 0;
    __syncthreads();
    #pragma unroll
    for (int k = 0; k < CHSZ / 1024; k++) {
        int e = ch * CHSZ + k * 1024 + t;
        if (e < NEDGES) atomicAdd(&cnt[dst[e] >> BSH], 1);
    }
    __syncthreads();
    for (int b = t; b < NBK; b += 1024) cntmat[b * NCH + ch] = cnt[b];
}

// ---------------------------------------------------------------------------
// Phase B: exclusive scan of cntmat (bucket-major), in place. 3 kernels.
// ---------------------------------------------------------------------------
__global__ __launch_bounds__(256) void scan_bsum(const int* __restrict__ x,
                                                 int* __restrict__ bsum) {
    const int t = threadIdx.x;
    int base = blockIdx.x * SCH + t * 4;
    int s = 0;
    #pragma unroll
    for (int q = 0; q < 4; q++) {
        int idx = base + q;
        if (idx < M_SCAN) s += x[idx];
    }
    #pragma unroll
    for (int d = 32; d > 0; d >>= 1) s += __shfl_down(s, d, 64);
    __shared__ int ws[4];
    int lane = t & 63, w = t >> 6;
    if (lane == 0) ws[w] = s;
    __syncthreads();
    if (t == 0) bsum[blockIdx.x] = ws[0] + ws[1] + ws[2] + ws[3];
}

__global__ __launch_bounds__(256) void scan_top(int* __restrict__ bsum) {
    const int t = threadIdx.x;
    int v = (t < NSB) ? bsum[t] : 0;
    int lane = t & 63, w = t >> 6;
    int s = v;
    #pragma unroll
    for (int d = 1; d < 64; d <<= 1) {
        int u = __shfl_up(s, d, 64);
        if (lane >= d) s += u;
    }
    __shared__ int ws[4];
    if (lane == 63) ws[w] = s;
    __syncthreads();
    int base = 0;
    #pragma unroll
    for (int q = 0; q < 4; q++) if (q < w) base += ws[q];
    if (t < NSB) bsum[t] = base + s - v;
}

__global__ __launch_bounds__(256) void scan_write(const int* __restrict__ bsum,
                                                  int* __restrict__ x) {
    const int t = threadIdx.x;
    int base = blockIdx.x * SCH + t * 4;
    int v[4]; int ts = 0;
    #pragma unroll
    for (int q = 0; q < 4; q++) {
        int idx = base + q;
        v[q] = (idx < M_SCAN) ? x[idx] : 0;
        ts += v[q];
    }
    int lane = t & 63, w = t >> 6;
    int s = ts;
    #pragma unroll
    for (int d = 1; d < 64; d <<= 1) {
        int u = __shfl_up(s, d, 64);
        if (lane >= d) s += u;
    }
    __shared__ int ws[4];
    if (lane == 63) ws[w] = s;
    __syncthreads();
    int wbase = 0;
    #pragma unroll
    for (int q = 0; q < 4; q++) if (q < w) wbase += ws[q];
    int run = bsum[blockIdx.x] + wbase + (s - ts);
    #pragma unroll
    for (int q = 0; q < 4; q++) {
        int idx = base + q;
        if (idx < M_SCAN) x[idx] = run;
        run += v[q];
    }
}

// ---------------------------------------------------------------------------
// Phase C: scatter into bucket-grouped records. LDS cursors, zero global
// atomics, segment-clustered writes. rec = src | et<<17 | (dst&127)<<21
// ---------------------------------------------------------------------------
__global__ __launch_bounds__(1024) void scatter_k(const int* __restrict__ src,
                                                  const int* __restrict__ dst,
                                                  const int* __restrict__ et,
                                                  const int* __restrict__ offmat,
                                                  int* __restrict__ rec) {
    __shared__ int offc[NBK];
    const int t = threadIdx.x, ch = blockIdx.x;
    for (int b = t; b < NBK; b += 1024) offc[b] = offmat[b * NCH + ch];
    __syncthreads();
    #pragma unroll
    for (int k = 0; k < CHSZ / 1024; k++) {
        int e = ch * CHSZ + k * 1024 + t;
        if (e < NEDGES) {
            int d = dst[e];
            int b = d >> BSH;
            int pos = atomicAdd(&offc[b], 1);
            rec[pos] = src[e] | (et[e] << 17) | ((d & 127) << 21);
        }
    }
}

// ---------------------------------------------------------------------------
// Phase D: per-bucket aggregation. 512 threads / 32 groups of 16 lanes.
// rec segment staged in LDS -> feat gather addresses have no vmem dependence.
// 4-edge register pipeline per group (launch_bounds(512,4) -> 128 VGPR cap).
// ---------------------------------------------------------------------------
#define EDGE_DECODE(r, sv, tv, lv) \
    int sv = (r) & 0x1FFFF; int tv = ((r) >> 17) & 15; int lv = (r) >> 21;

#define EDGE_MSG(F0, F1, F2, F3, tyv, ldv)                                  \
    {                                                                        \
        const float4* pa_ = (const float4*)(At2 + (tyv) * ATY + i * ASTR);   \
        float4 A0_ = pa_[0], A1_ = pa_[1], A2_ = pa_[2], A3_ = pa_[3];       \
        float m_;                                                            \
        m_  = A0_.x*(F0).x + A0_.y*(F0).y + A0_.z*(F0).z + A0_.w*(F0).w;     \
        m_ += A1_.x*(F1).x + A1_.y*(F1).y + A1_.z*(F1).z + A1_.w*(F1).w;     \
        m_ += A2_.x*(F2).x + A2_.y*(F2).y + A2_.z*(F2).z + A2_.w*(F2).w;     \
        m_ += A3_.x*(F3).x + A3_.y*(F3).y + A3_.z*(F3).z + A3_.w*(F3).w;     \
        atomicAdd(&acc[(ldv) * 17 + i], m_);                                 \
    }

__global__ __launch_bounds__(512, 4) void agg_k(const float* __restrict__ feat,
                                                const int* __restrict__ offmat,
                                                const int* __restrict__ rec,
                                                const float* __restrict__ edge_emb,
                                                float* __restrict__ magg) {
    __shared__ float At2[NTYPE * ATY];     // 20.5 KB
    __shared__ float acc[128 * 17];        // 8.7 KB
    __shared__ int   recs[RECCAP];         // 10.2 KB
    const int t = threadIdx.x, b = blockIdx.x;

    #pragma unroll
    for (int idx = t; idx < NTYPE * MSG * HID; idx += 512) {
        int ty  = idx >> 8;
        int rem = idx & 255;
        int ii  = rem >> 4;
        int h   = rem & 15;
        At2[ty * ATY + ii * ASTR + h] = edge_emb[idx];
    }
    for (int k = t; k < 128 * 17; k += 512) acc[k] = 0.0f;

    const int jb  = offmat[b * NCH];
    const int je  = (b == NBK - 1) ? NEDGES : offmat[(b + 1) * NCH];
    const int len = je - jb;
    const int lcap = len < RECCAP ? len : RECCAP;
    for (int k = t; k < lcap; k += 512) recs[k] = rec[jb + k];
    __syncthreads();

    const int g = t >> 4, i = t & 15;

    int j = g;
    // 4-deep batches entirely from LDS-staged records
    for (; j + 96 < lcap; j += 128) {
        int r0 = recs[j], r1 = recs[j + 32], r2 = recs[j + 64], r3 = recs[j + 96];
        EDGE_DECODE(r0, s0, ty0, ld0)
        EDGE_DECODE(r1, s1, ty1, ld1)
        EDGE_DECODE(r2, s2, ty2, ld2)
        EDGE_DECODE(r3, s3, ty3, ld3)
        const float4* p0 = (const float4*)(feat + (size_t)s0 * HID);
        const float4* p1 = (const float4*)(feat + (size_t)s1 * HID);
        const float4* p2 = (const float4*)(feat + (size_t)s2 * HID);
        const float4* p3 = (const float4*)(feat + (size_t)s3 * HID);
        float4 F00 = p0[0], F01 = p0[1], F02 = p0[2], F03 = p0[3];
        float4 F10 = p1[0], F11 = p1[1], F12 = p1[2], F13 = p1[3];
        float4 F20 = p2[0], F21 = p2[1], F22 = p2[2], F23 = p2[3];
        float4 F30 = p3[0], F31 = p3[1], F32 = p3[2], F33 = p3[3];
        EDGE_MSG(F00, F01, F02, F03, ty0, ld0)
        EDGE_MSG(F10, F11, F12, F13, ty1, ld1)
        EDGE_MSG(F20, F21, F22, F23, ty2, ld2)
        EDGE_MSG(F30, F31, F32, F33, ty3, ld3)
    }
    // single-edge tail from LDS
    for (; j < lcap; j += 32) {
        int r0 = recs[j];
        EDGE_DECODE(r0, s0, ty0, ld0)
        const float4* p0 = (const float4*)(feat + (size_t)s0 * HID);
        float4 F00 = p0[0], F01 = p0[1], F02 = p0[2], F03 = p0[3];
        EDGE_MSG(F00, F01, F02, F03, ty0, ld0)
    }
    // overflow tail from global (only if segment > RECCAP; keeps correctness)
    for (; j < len; j += 32) {
        int r0 = rec[jb + j];
        EDGE_DECODE(r0, s0, ty0, ld0)
        const float4* p0 = (const float4*)(feat + (size_t)s0 * HID);
        float4 F00 = p0[0], F01 = p0[1], F02 = p0[2], F03 = p0[3];
        EDGE_MSG(F00, F01, F02, F03, ty0, ld0)
    }
    __syncthreads();

    const int nb = b << BSH;
    #pragma unroll
    for (int k = t; k < 128 * 16; k += 512) {
        int ln = k >> 4, ii = k & 15;
        int n = nb + ln;
        if (n < NNODES) magg[(size_t)n * MSG + ii] = acc[ln * 17 + ii];
    }
}

// ---------------------------------------------------------------------------
// Fallback atomic edge kernel (only if ws too small)
// ---------------------------------------------------------------------------
__global__ __launch_bounds__(256) void ggnn_edge(
    const float* __restrict__ feat,
    const int* __restrict__ src,
    const int* __restrict__ dst,
    const int* __restrict__ etype,
    const float* __restrict__ edge_emb,
    float* __restrict__ magg)
{
    __shared__ float At[NTYPE * MSG * HID];
    for (int idx = threadIdx.x; idx < NTYPE * MSG * HID; idx += 256) {
        int ty = idx >> 8, rem = idx & 255, i = rem >> 4, hh = rem & 15;
        At[(ty << 8) | (hh << 4) | i] = edge_emb[idx];
    }
    __syncthreads();
    const long long total = (long long)NEDGES * MSG;
    for (long long w = (long long)blockIdx.x * 256 + threadIdx.x; w < total;
         w += (long long)gridDim.x * 256) {
        const int e = (int)(w >> 4);
        const int i = (int)(w & 15);
        const int s = src[e];
        const int d = dst[e];
        const int ty = etype[e];
        const float4* fp = (const float4*)(feat + (size_t)s * HID);
        const float4 f0 = fp[0], f1 = fp[1], f2 = fp[2], f3 = fp[3];
        const float* a = At + (ty << 8) + i;
        float m;
        m  = a[0*16]*f0.x + a[1*16]*f0.y + a[2*16]*f0.z + a[3*16]*f0.w;
        m += a[4*16]*f1.x + a[5*16]*f1.y + a[6*16]*f1.z + a[7*16]*f1.w;
        m += a[8*16]*f2.x + a[9*16]*f2.y + a[10*16]*f2.z + a[11*16]*f2.w;
        m += a[12*16]*f3.x + a[13*16]*f3.y + a[14*16]*f3.z + a[15*16]*f3.w;
        atomicAdd(magg + (size_t)d * MSG + i, m);
    }
}

// ---------------------------------------------------------------------------
// Node kernel: GRU -> hnew in LDS -> coalesced output head.
// ---------------------------------------------------------------------------
__global__ __launch_bounds__(256) void node_k(
    const float* __restrict__ feat,
    const float* __restrict__ magg,
    const float* __restrict__ W_ih,
    const float* __restrict__ W_hh,
    const float* __restrict__ b_ih,
    const float* __restrict__ b_hh,
    const float* __restrict__ W_out,
    const float* __restrict__ b_out,
    float* __restrict__ out)
{
    __shared__ float hn_s[256 * 20];
    __shared__ float Wo_s[NCLS * 17];
    __shared__ float bo_s[NCLS];

    const int t = threadIdx.x;
    for (int k = t; k < NCLS * 16; k += 256) Wo_s[(k >> 4) * 17 + (k & 15)] = W_out[k];
    if (t < NCLS) bo_s[t] = b_out[t];

    const int n = blockIdx.x * 256 + t;
    if (n < NNODES) {
        float hv[HID], mv[MSG];
        const float4* hp = (const float4*)(feat + (size_t)n * HID);
        const float4* mp = (const float4*)(magg + (size_t)n * MSG);
        #pragma unroll
        for (int q = 0; q < 4; q++) {
            float4 a = hp[q];
            hv[4*q+0] = a.x; hv[4*q+1] = a.y; hv[4*q+2] = a.z; hv[4*q+3] = a.w;
            float4 c = mp[q];
            mv[4*q+0] = c.x; mv[4*q+1] = c.y; mv[4*q+2] = c.z; mv[4*q+3] = c.w;
        }
        #pragma unroll
        for (int i = 0; i < HID; i++) {
            float xr = b_ih[i], xz = b_ih[16 + i], xn = b_ih[32 + i];
            float hr = b_hh[i], hz = b_hh[16 + i], hn = b_hh[32 + i];
            #pragma unroll
            for (int j = 0; j < HID; j++) {
                xr += W_ih[(i)      * 16 + j] * mv[j];
                xz += W_ih[(16 + i) * 16 + j] * mv[j];
                xn += W_ih[(32 + i) * 16 + j] * mv[j];
                hr += W_hh[(i)      * 16 + j] * hv[j];
                hz += W_hh[(16 + i) * 16 + j] * hv[j];
                hn += W_hh[(32 + i) * 16 + j] * hv[j];
            }
            float r  = sigmoid_f(xr + hr);
            float z  = sigmoid_f(xz + hz);
            float nn = tanh_f(xn + r * hn);
            hn_s[t * 20 + i] = (1.0f - z) * nn + z * hv[i];
        }
    }
    __syncthreads();

    const int c = t & 63;
    float wr[16];
    #pragma unroll
    for (int j = 0; j < 16; j++) wr[j] = Wo_s[c * 17 + j];
    const float bo = bo_s[c];
    const int nb = blockIdx.x * 256;

    #pragma unroll 4
    for (int it = 0; it < 64; it++) {
        int k = t + 256 * it;
        int ln = k >> 6;
        int n2 = nb + ln;
        if (n2 < NNODES) {
            const float4* hq = (const float4*)(hn_s + ln * 20);
            float4 h0 = hq[0], h1 = hq[1], h2 = hq[2], h3 = hq[3];
            float a = bo;
            a += wr[0]*h0.x + wr[1]*h0.y + wr[2]*h0.z + wr[3]*h0.w;
            a += wr[4]*h1.x + wr[5]*h1.y + wr[6]*h1.z + wr[7]*h1.w;
            a += wr[8]*h2.x + wr[9]*h2.y + wr[10]*h2.z + wr[11]*h2.w;
            a += wr[12]*h3.x + wr[13]*h3.y + wr[14]*h3.z + wr[15]*h3.w;
            out[(size_t)n2 * NCLS + c] = a;
        }
    }
}

extern "C" void kernel_launch(void* const* d_in, const int* in_sizes, int n_in,
                              void* d_out, int out_size, void* d_ws, size_t ws_size,
                              hipStream_t stream) {
    const float* feat     = (const float*)d_in[0];
    const int*   src      = (const int*)d_in[1];
    const int*   dst      = (const int*)d_in[2];
    const int*   etype    = (const int*)d_in[3];
    const float* edge_emb = (const float*)d_in[4];
    const float* W_ih     = (const float*)d_in[5];
    const float* W_hh     = (const float*)d_in[6];
    const float* b_ih     = (const float*)d_in[7];
    const float* b_hh     = (const float*)d_in[8];
    const float* W_out    = (const float*)d_in[9];
    const float* b_out    = (const float*)d_in[10];
    float* out = (float*)d_out;

    // workspace layout (4-byte elements): 13.4 MB total
    float* magg   = (float*)d_ws;                         // NNODES*16
    int*   offmat = (int*)d_ws + (size_t)NNODES * MSG;    // M_SCAN
    int*   bsum   = offmat + M_SCAN;                      // NSB (pad 256)
    int*   rec    = bsum + 256;                           // NEDGES
    size_t need   = ((size_t)NNODES * MSG + M_SCAN + 256 + NEDGES) * 4;

    if (ws_size >= need) {
        hist_k    <<<NCH, 1024, 0, stream>>>(dst, offmat);
        scan_bsum <<<NSB, 256, 0, stream>>>(offmat, bsum);
        scan_top  <<<1, 256, 0, stream>>>(bsum);
        scan_write<<<NSB, 256, 0, stream>>>(bsum, offmat);
        scatter_k <<<NCH, 1024, 0, stream>>>(src, dst, etype, offmat, rec);
        agg_k     <<<NBK, 512, 0, stream>>>(feat, offmat, rec, edge_emb, magg);
    } else {
        hipMemsetAsync(magg, 0, (size_t)NNODES * MSG * sizeof(float), stream);
        ggnn_edge<<<2560, 256, 0, stream>>>(feat, src, dst, etype, edge_emb, magg);
    }
    node_k<<<(NNODES + 255) / 256, 256, 0, stream>>>(
        feat, magg, W_ih, W_hh, b_ih, b_hh, W_out, b_out, out);
}